// Round 2
// baseline (305.875 us; speedup 1.0000x reference)
//
#include <hip/hip_runtime.h>
#include <hip/hip_bf16.h>
#include <math.h>

// Problem constants
// B=32, C=64 (Cin==Cout), N=8192, modes F=32, L=20 segments, M=8 Chebyshev
#define NN    8192
#define NROWS 2048      // B*C
#define FF    32
#define LM    160       // L*M

// Workspace layout (float offsets)
static constexpr int TRIG  = 0;         // [64][8192]: rows 0..31 cos(2pi f n/N), 32..63 sin
static constexpr int W1RT  = 524288;    // [f][i][o] 32*64*64
static constexpr int W1IT  = 655360;
static constexpr int GWT   = 786432;    // [i][o] 64*64
static constexpr int AR_   = 790528;    // [160][32]
static constexpr int AI_   = 795648;
static constexpr int WL_   = 800768;    // [160]
static constexpr int WR_   = 800928;
static constexpr int IL_   = 801088;    // int [160]
static constexpr int IR_   = 801248;
static constexpr int XR_   = 801408;    // [2048][32]
static constexpr int XI_   = 866944;
static constexpr int GN_   = 932480;    // [2048][32]
static constexpr int ARAI  = 998016;    // [2048][64]: [0..31]=cos coeff, [32..63]=sin coeff
// total = 1129088 floats = 4.31 MB

#define PI_D 3.14159265358979323846

// ---------------- A1: trig table ----------------
__global__ __launch_bounds__(256) void k_trig(float* __restrict__ ws) {
  int idx = blockIdx.x * 256 + threadIdx.x;   // 0..262143
  int f = idx >> 13, n = idx & (NN - 1);
  int p = (f * n) & (NN - 1);
  float ang = (float)p * (float)(2.0 * PI_D / (double)NN);
  float s, c;
  sincosf(ang, &s, &c);
  ws[TRIG + f * NN + n] = c;
  ws[TRIG + (32 + f) * NN + n] = s;
}

// ---------------- A2: CFT constant tables (double precision) ----------------
__global__ __launch_bounds__(256) void k_cft_tables(float* __restrict__ ws) {
  int j = threadIdx.x;
  if (j >= LM) return;
  int l = j >> 3, m = j & 7;      // j = l*8 + m ; m doubles as Chebyshev order k
  double cheb[8];
  #pragma unroll
  for (int mm = 0; mm < 8; ++mm)
    cheb[mm] = -cos((2.0 * mm + 1.0) * PI_D / 16.0);

  // interpolation index/weights at t_seg(l, m)
  double v = (double)l * 0.05 + 0.025 * (cheb[m] + 1.0);
  int r = (int)(v * 8191.0);
  while ((double)r / 8191.0 < v) ++r;
  while (r > 0 && (double)(r - 1) / 8191.0 >= v) --r;
  if (r > 8191) r = 8191;
  int le = r - 1; if (le < 0) le = 0;
  double tl = (double)le / 8191.0, tr = (double)r / 8191.0;
  double den = (tr - tl == 0.0) ? 1.0 : (tr - tl);
  double wr = (v - tl) / den;
  ws[WL_ + j] = (float)(1.0 - wr);
  ws[WR_ + j] = (float)wr;
  ((int*)ws)[IL_ + j] = le;
  ((int*)ws)[IR_ + j] = r;

  // combined quadrature weights Ar/Ai
  int kk = m;
  for (int f = 0; f < FF; ++f) {
    double Wr = 0.0, Wi = 0.0;
    #pragma unroll
    for (int mm = 0; mm < 8; ++mm) {
      double T = cos((double)kk * acos(cheb[mm]));
      double ang = cheb[mm] * (double)f * (PI_D * 0.05);
      Wr += T * cos(ang);
      Wi += T * (-sin(ang));
    }
    Wr *= 0.025; Wi *= 0.025;
    double phi = 2.0 * PI_D * ((double)l * 0.05) * (double)f;
    double cs = cos(phi), sn = sin(phi);
    ws[AR_ + j * FF + f] = (float)(Wr * cs + Wi * sn);
    ws[AI_ + j * FF + f] = (float)(-Wr * sn + Wi * cs);
  }
}

// ---------------- A3: transposes ----------------
// FIX (R1): grid was 2x too large; f ran 0..63 and writes spilled over the
// W1IT/GWT/AR_/AI_/IL_/IR_ tables -> k_fwd used garbage ints as x indices ->
// GPU memory fault. Now 512 blocks + explicit guard.
__global__ __launch_bounds__(256) void k_transpose(const float* __restrict__ w1r,
                                                   const float* __restrict__ w1i,
                                                   const float* __restrict__ gw,
                                                   float* __restrict__ ws) {
  int idx = blockIdx.x * 256 + threadIdx.x;   // 0..131071
  if (idx >= 32 * 64 * 64) return;
  int o = idx & 63, i = (idx >> 6) & 63, f = idx >> 12;   // f in 0..31
  ws[W1RT + (f * 64 + i) * 64 + o] = w1r[(i * 64 + o) * FF + f];
  ws[W1IT + (f * 64 + i) * 64 + o] = w1i[(i * 64 + o) * FF + f];
  if (idx < 4096) {
    // gwT[i][o] = gate_w[o][i]
    ws[GWT + idx] = gw[(idx & 63) * 64 + (idx >> 6)];
  }
}

// ---------------- B: forward truncated DFT + CFT magnitude + LayerNorm ----------------
__global__ __launch_bounds__(256) void k_fwd(const float* __restrict__ x,
                                             const float* __restrict__ gamma,
                                             const float* __restrict__ beta,
                                             float* __restrict__ ws) {
  const int row = blockIdx.x;                 // 0..2047
  const float* __restrict__ xr = x + (size_t)row * NN;
  const int t = threadIdx.x;
  const int f = t >> 3, c8 = t & 7;

  // thread covers n = 32*i + 4*c8 + k, k<4, i<256; rotation step = 2pi*f*32/N
  float C0=0.f,S0=0.f,C1=0.f,S1=0.f,C2=0.f,S2=0.f,C3=0.f,S3=0.f;
  float dc, ds;
  sincosf((float)f * (float)(2.0 * PI_D / 256.0), &ds, &dc);
  const float C2PIN = (float)(2.0 * PI_D / (double)NN);
  float c = 1.f, s = 0.f;
  for (int o2 = 0; o2 < 4; ++o2) {
    int i0 = o2 * 64;
    int p = (f * (32 * i0 + 4 * c8)) & (NN - 1);
    sincosf((float)p * C2PIN, &s, &c);
    #pragma unroll 4
    for (int ii = 0; ii < 64; ++ii) {
      int i = i0 + ii;
      float4 xv = *(const float4*)(xr + 32 * i + 4 * c8);
      C0 = fmaf(xv.x, c, C0); S0 = fmaf(xv.x, s, S0);
      C1 = fmaf(xv.y, c, C1); S1 = fmaf(xv.y, s, S1);
      C2 = fmaf(xv.z, c, C2); S2 = fmaf(xv.z, s, S2);
      C3 = fmaf(xv.w, c, C3); S3 = fmaf(xv.w, s, S3);
      float cn = fmaf(c, dc, -s * ds);
      s = fmaf(s, dc, c * ds);
      c = cn;
    }
  }
  // fold the 4 sub-phase accumulators: (C,S) += (Ck + iSk) * e^{i 2pi f k / N}
  float Ct = C0, St = S0;
  {
    float base = (float)f * C2PIN;
    float ck, sk;
    sincosf(base, &sk, &ck);        Ct += C1*ck - S1*sk; St += S1*ck + C1*sk;
    sincosf(2.f*base, &sk, &ck);    Ct += C2*ck - S2*sk; St += S2*ck + C2*sk;
    sincosf(3.f*base, &sk, &ck);    Ct += C3*ck - S3*sk; St += S3*ck + C3*sk;
  }
  // reduce over c8 (lane bits 0..2)
  Ct += __shfl_xor(Ct, 1); St += __shfl_xor(St, 1);
  Ct += __shfl_xor(Ct, 2); St += __shfl_xor(St, 2);
  Ct += __shfl_xor(Ct, 4); St += __shfl_xor(St, 4);
  if (c8 == 0) {
    ws[XR_ + row * FF + f] = Ct;
    ws[XI_ + row * FF + f] = -St;   // rfft imag = -sum x sin
  }

  // ---- CFT magnitude + LayerNorm ----
  __shared__ float seg_s[LM];
  if (t < LM) {
    int il = ((const int*)ws)[IL_ + t];
    int ir = ((const int*)ws)[IR_ + t];
    seg_s[t] = ws[WL_ + t] * xr[il] + ws[WR_ + t] * xr[ir];
  }
  __syncthreads();
  if (t < FF) {
    float re = 0.f, im = 0.f;
    #pragma unroll 8
    for (int j = 0; j < LM; ++j) {
      float sv = seg_s[j];
      re = fmaf(sv, ws[AR_ + j * FF + t], re);
      im = fmaf(sv, ws[AI_ + j * FF + t], im);
    }
    float mag = sqrtf(re * re + im * im);
    float mu = mag;
    mu += __shfl_xor(mu, 1);  mu += __shfl_xor(mu, 2);  mu += __shfl_xor(mu, 4);
    mu += __shfl_xor(mu, 8);  mu += __shfl_xor(mu, 16);
    mu *= (1.0f / 32.0f);
    float d = mag - mu;
    float vv = d * d;
    vv += __shfl_xor(vv, 1);  vv += __shfl_xor(vv, 2);  vv += __shfl_xor(vv, 4);
    vv += __shfl_xor(vv, 8);  vv += __shfl_xor(vv, 16);
    vv *= (1.0f / 32.0f);
    float g = d / sqrtf(vv + 1e-5f) * gamma[t] + beta[t];
    ws[GN_ + row * FF + t] = g;
  }
}

// ---------------- C: gate (LN -> 1x1 conv -> sigmoid) + complex channel mix ----------------
__global__ __launch_bounds__(64) void k_gate(float* __restrict__ ws) {
  int bidx = blockIdx.x;                 // b*32 + f
  int b = bidx >> 5, f = bidx & 31;
  int o = threadIdx.x;
  __shared__ float gn[64], gr[64], gi[64];
  int rowb = b * 64;
  gn[o] = ws[GN_ + (rowb + o) * FF + f];
  float xre = ws[XR_ + (rowb + o) * FF + f];
  float xim = ws[XI_ + (rowb + o) * FF + f];
  __syncthreads();
  float acc = 0.f;
  #pragma unroll 16
  for (int i = 0; i < 64; ++i)
    acc = fmaf(ws[GWT + i * 64 + o], gn[i], acc);
  float gate = 1.0f / (1.0f + expf(-acc));
  gr[o] = xre * gate;
  gi[o] = xim * gate;
  __syncthreads();
  float Yr = 0.f, Yi = 0.f;
  const float* __restrict__ w1rt = ws + W1RT + f * 4096;
  const float* __restrict__ w1it = ws + W1IT + f * 4096;
  #pragma unroll 8
  for (int i = 0; i < 64; ++i) {
    float a = gr[i], bb2 = gi[i];
    float wr = w1rt[i * 64 + o], wi = w1it[i * 64 + o];
    Yr = fmaf(a, wr, Yr); Yr = fmaf(-bb2, wi, Yr);
    Yi = fmaf(a, wi, Yi); Yi = fmaf(bb2, wr, Yi);
  }
  // irfft coefficients: out[n] = sum_f ar[f] cos + ai[f] sin ; DC imag ignored (numpy C2R)
  float* A = ws + ARAI + (size_t)(rowb + o) * 64;
  if (f == 0) {
    A[0]  = Yr * (1.0f / (float)NN);
    A[32] = 0.0f;
  } else {
    A[f]      = Yr * (2.0f / (float)NN);
    A[32 + f] = -Yi * (2.0f / (float)NN);
  }
}

// ---------------- D: inverse (2048x64)@(64x8192) GEMM vs trig table ----------------
__global__ __launch_bounds__(256) void k_inv(const float* __restrict__ ws,
                                             float* __restrict__ out) {
  __shared__ __align__(16) float T_s[64 * 256];   // 64 KB
  int blk = blockIdx.x;
  int bb = blk >> 5, cc = blk & 31;               // 32 row-tiles x 32 col-tiles(256)
  int t = threadIdx.x;
  int cx = t & 15, ry = t >> 4;

  const float* __restrict__ trig = ws + TRIG;
  {
    float4* T4 = (float4*)T_s;
    const int base = cc * 256;
    #pragma unroll
    for (int r2 = 0; r2 < 16; ++r2) {
      int q = t + 256 * r2;       // float4 index 0..4095
      int j = q >> 6, c4 = q & 63;
      T4[q] = *(const float4*)(trig + (size_t)j * NN + base + c4 * 4);
    }
  }
  __syncthreads();

  float acc[4][16];
  #pragma unroll
  for (int r = 0; r < 4; ++r)
    #pragma unroll
    for (int k = 0; k < 16; ++k) acc[r][k] = 0.f;

  const float* __restrict__ Ab = ws + ARAI + (size_t)(bb * 64) * 64;
  for (int j0 = 0; j0 < 64; j0 += 4) {
    float4 av[4];
    #pragma unroll
    for (int r = 0; r < 4; ++r)
      av[r] = *(const float4*)(Ab + (ry * 4 + r) * 64 + j0);
    #pragma unroll
    for (int jj = 0; jj < 4; ++jj) {
      int j = j0 + jj;
      const float* Trow = &T_s[j * 256 + cx * 4];
      float4 t0 = *(const float4*)(Trow);
      float4 t1 = *(const float4*)(Trow + 64);
      float4 t2 = *(const float4*)(Trow + 128);
      float4 t3 = *(const float4*)(Trow + 192);
      #pragma unroll
      for (int r = 0; r < 4; ++r) {
        float a = ((const float*)&av[r])[jj];
        acc[r][0]  = fmaf(a, t0.x, acc[r][0]);
        acc[r][1]  = fmaf(a, t0.y, acc[r][1]);
        acc[r][2]  = fmaf(a, t0.z, acc[r][2]);
        acc[r][3]  = fmaf(a, t0.w, acc[r][3]);
        acc[r][4]  = fmaf(a, t1.x, acc[r][4]);
        acc[r][5]  = fmaf(a, t1.y, acc[r][5]);
        acc[r][6]  = fmaf(a, t1.z, acc[r][6]);
        acc[r][7]  = fmaf(a, t1.w, acc[r][7]);
        acc[r][8]  = fmaf(a, t2.x, acc[r][8]);
        acc[r][9]  = fmaf(a, t2.y, acc[r][9]);
        acc[r][10] = fmaf(a, t2.z, acc[r][10]);
        acc[r][11] = fmaf(a, t2.w, acc[r][11]);
        acc[r][12] = fmaf(a, t3.x, acc[r][12]);
        acc[r][13] = fmaf(a, t3.y, acc[r][13]);
        acc[r][14] = fmaf(a, t3.z, acc[r][14]);
        acc[r][15] = fmaf(a, t3.w, acc[r][15]);
      }
    }
  }
  #pragma unroll
  for (int r = 0; r < 4; ++r) {
    int row = bb * 64 + ry * 4 + r;
    float* op = out + (size_t)row * NN + cc * 256;
    #pragma unroll
    for (int q = 0; q < 4; ++q) {
      float4 v = make_float4(acc[r][4*q+0], acc[r][4*q+1], acc[r][4*q+2], acc[r][4*q+3]);
      *(float4*)(op + q * 64 + cx * 4) = v;
    }
  }
}

extern "C" void kernel_launch(void* const* d_in, const int* in_sizes, int n_in,
                              void* d_out, int out_size, void* d_ws, size_t ws_size,
                              hipStream_t stream) {
  const float* x     = (const float*)d_in[0];   // (32,64,8192)
  const float* w1r   = (const float*)d_in[1];   // (64,64,32)
  const float* w1i   = (const float*)d_in[2];   // (64,64,32)
  const float* gw    = (const float*)d_in[3];   // (64,64)
  const float* gamma = (const float*)d_in[4];   // (32,)
  const float* beta  = (const float*)d_in[5];   // (32,)
  float* out = (float*)d_out;                   // (32,64,8192)
  float* ws = (float*)d_ws;

  hipLaunchKernelGGL(k_trig,       dim3(1024), dim3(256), 0, stream, ws);
  hipLaunchKernelGGL(k_cft_tables, dim3(1),    dim3(256), 0, stream, ws);
  hipLaunchKernelGGL(k_transpose,  dim3(512),  dim3(256), 0, stream, w1r, w1i, gw, ws);
  hipLaunchKernelGGL(k_fwd,        dim3(2048), dim3(256), 0, stream, x, gamma, beta, ws);
  hipLaunchKernelGGL(k_gate,       dim3(1024), dim3(64),  0, stream, ws);
  hipLaunchKernelGGL(k_inv,        dim3(1024), dim3(256), 0, stream, ws, out);
}